// Round 2
// baseline (3960.617 us; speedup 1.0000x reference)
//
#include <hip/hip_runtime.h>
#include <hip/hip_bf16.h>

// Problem: N=128 nodes, T=512, I=32, H=256, 2-layer per-node LSTM + LayerNorm.
// lstm_rec v2: 256 thr/WG, 4-way k-split, DPP quad reduction, 1 barrier/step.

typedef _Float16 half2_t __attribute__((ext_vector_type(2)));
typedef _Float16 half8_t __attribute__((ext_vector_type(8)));
typedef float floatx4 __attribute__((ext_vector_type(4)));

__device__ __forceinline__ unsigned pk(float a, float b) {
  half2_t h = { (_Float16)a, (_Float16)b };
  return __builtin_bit_cast(unsigned, h);
}
__device__ __forceinline__ float fdot2(unsigned w, unsigned h, float c) {
  return __builtin_amdgcn_fdot2(__builtin_bit_cast(half2_t, w),
                                __builtin_bit_cast(half2_t, h), c, false);
}
__device__ __forceinline__ float h2f(unsigned short u) {
  return (float)__builtin_bit_cast(_Float16, u);
}
__device__ __forceinline__ unsigned short f2h(float f) {
  return __builtin_bit_cast(unsigned short, (_Float16)f);
}
__device__ __forceinline__ float sigmf(float x) {
  return __builtin_amdgcn_rcpf(1.f + __expf(-x));
}
__device__ __forceinline__ float tanh_(float x) {
  return 2.f * sigmf(2.f * x) - 1.f;
}
__device__ __forceinline__ floatx4 mfma16(half8_t a, half8_t b, floatx4 c) {
  return __builtin_amdgcn_mfma_f32_16x16x32_f16(a, b, c, 0, 0, 0);
}
// DPP quad-perm rotate: lane i <- lane (i-d)&3 within each quad.
template<int CTRL>
__device__ __forceinline__ float dppf(float x) {
  return __builtin_bit_cast(
      float, __builtin_amdgcn_update_dpp(0, __builtin_bit_cast(int, x), CTRL,
                                         0xf, 0xf, true));
}

// ---------------------------------------------------------------------------
// GEMM: C[n][m][g] = sum_k A[n][m][k] * B[n][g][k], C stored f16. (unchanged)
// ---------------------------------------------------------------------------
template<int K, int KT, bool AF16>
__global__ __launch_bounds__(256)
void gemm_xw(const void* __restrict__ Ap, const float* __restrict__ Bp,
             unsigned short* __restrict__ Cp)
{
  __shared__ unsigned short As[128][KT + 8];
  __shared__ unsigned short Bs[128][KT + 8];
  const int tid = threadIdx.x;
  const int node = blockIdx.y;
  const int mt = blockIdx.x >> 3;
  const int nt = blockIdx.x & 7;
  const int lane = tid & 63, wv = tid >> 6;
  const int wr = wv >> 1, wc = wv & 1;
  const int lm = lane & 15, lk = (lane >> 4) * 8;

  floatx4 zero = {0.f, 0.f, 0.f, 0.f};
  floatx4 acc[4][4];
#pragma unroll
  for (int i = 0; i < 4; ++i)
#pragma unroll
    for (int j = 0; j < 4; ++j) acc[i][j] = zero;

  for (int kt = 0; kt < K; kt += KT) {
    if (AF16) {
      const unsigned short* A = (const unsigned short*)Ap + (size_t)node * 512 * K;
      const int CPR = KT / 8;
#pragma unroll
      for (int c = tid; c < 128 * CPR; c += 256) {
        int r = c / CPR, cc = (c % CPR) * 8;
        *(uint4*)&As[r][cc] =
            *(const uint4*)(A + (size_t)(mt * 128 + r) * K + kt + cc);
      }
    } else {
      const float* A = (const float*)Ap + (size_t)node * 512 * K;
      const int CPR = KT / 4;
#pragma unroll
      for (int c = tid; c < 128 * CPR; c += 256) {
        int r = c / CPR, cc = (c % CPR) * 4;
        float4 v = *(const float4*)(A + (size_t)(mt * 128 + r) * K + kt + cc);
        uint2 p = make_uint2(pk(v.x, v.y), pk(v.z, v.w));
        *(uint2*)&As[r][cc] = p;
      }
    }
    {
      const float* B = Bp + (size_t)node * 1024 * K;
      const int CPR = KT / 4;
#pragma unroll
      for (int c = tid; c < 128 * CPR; c += 256) {
        int r = c / CPR, cc = (c % CPR) * 4;
        float4 v = *(const float4*)(B + (size_t)(nt * 128 + r) * K + kt + cc);
        uint2 p = make_uint2(pk(v.x, v.y), pk(v.z, v.w));
        *(uint2*)&Bs[r][cc] = p;
      }
    }
    __syncthreads();
#pragma unroll
    for (int ks = 0; ks < KT / 32; ++ks) {
      half8_t af[4], bf[4];
#pragma unroll
      for (int i = 0; i < 4; ++i)
        af[i] = *(const half8_t*)&As[wr * 64 + i * 16 + lm][ks * 32 + lk];
#pragma unroll
      for (int j = 0; j < 4; ++j)
        bf[j] = *(const half8_t*)&Bs[wc * 64 + j * 16 + lm][ks * 32 + lk];
#pragma unroll
      for (int i = 0; i < 4; ++i)
#pragma unroll
        for (int j = 0; j < 4; ++j)
          acc[i][j] = mfma16(af[i], bf[j], acc[i][j]);
    }
    __syncthreads();
  }
  unsigned short* C = Cp + (size_t)node * 512 * 1024;
#pragma unroll
  for (int i = 0; i < 4; ++i)
#pragma unroll
    for (int j = 0; j < 4; ++j)
#pragma unroll
      for (int r = 0; r < 4; ++r) {
        int row = mt * 128 + wr * 64 + i * 16 + (lane >> 4) * 4 + r;
        int col = nt * 128 + wc * 64 + j * 16 + lm;
        C[(size_t)row * 1024 + col] = f2h(acc[i][j][r]);
      }
}

// ---------------------------------------------------------------------------
// lstm_rec v2. 256 threads (4 waves), one WG per node.
// Lane l (wave w): r = l&3 (k-quarter), owns unit u = w*64 + l.
// Slice s = G*4 + j: row G*256 + u0 + ((r+j)&3), k in [64r, 64r+64),
// where u0 = w*64 + (l>>2)*4. 24 dwords/slice in VGPR, 8 dwords/slice in LDS.
// Reduction: A_G = acc[G][0] + rot1(acc[G][1]) + rot2(acc[G][2]) + rot3(acc[G][3])
// lands the full pre-activation for unit u on its owning lane.
// ---------------------------------------------------------------------------
template<bool WRITE_HS, bool FINAL>
__global__ __launch_bounds__(256, 1)
void lstm_rec(const unsigned short* __restrict__ xW,   // [n][t][1024] f16 (no bias)
              const float* __restrict__ Whh,           // [n][1024][256] fp32
              const float* __restrict__ bih, const float* __restrict__ bhh,
              unsigned short* __restrict__ hs,         // [n][t][256] f16 (out)
              const float* __restrict__ gamma, const float* __restrict__ beta,
              float* __restrict__ out)                 // [n][256] fp32
{
  __shared__ uint4 lwL[16][2][256];                    // 128 KB weight tails
  __shared__ __align__(16) unsigned short hbuf[2][256];
  __shared__ float red[256];
  __shared__ float redv[2];

  const int tid = threadIdx.x;
  const int n = blockIdx.x;
  const int l = tid & 63, w = tid >> 6;
  const int r = l & 3;
  const int u0 = w * 64 + (l >> 2) * 4;
  const int u = w * 64 + l;                            // owned unit

  // bias for the 4 gate rows of unit u
  float bias[4];
#pragma unroll
  for (int G = 0; G < 4; ++G)
    bias[G] = bih[n * 1024 + G * 256 + u] + bhh[n * 1024 + G * 256 + u];

  // ---- prologue: load + pack weights ----
  unsigned wv[16 * 24];
#pragma unroll
  for (int G = 0; G < 4; ++G)
#pragma unroll
    for (int j = 0; j < 4; ++j) {
      const int s = G * 4 + j;
      const int row = G * 256 + u0 + ((r + j) & 3);
      const float4* Wp =
          (const float4*)(Whh + ((size_t)n * 1024 + row) * 256 + 64 * r);
#pragma unroll
      for (int m = 0; m < 12; ++m) {
        float4 v = Wp[m];
        wv[s * 24 + 2 * m]     = pk(v.x, v.y);
        wv[s * 24 + 2 * m + 1] = pk(v.z, v.w);
      }
      float4 a = Wp[12], b = Wp[13];
      lwL[s][0][tid] = make_uint4(pk(a.x, a.y), pk(a.z, a.w), pk(b.x, b.y), pk(b.z, b.w));
      float4 c4 = Wp[14], d4 = Wp[15];
      lwL[s][1][tid] = make_uint4(pk(c4.x, c4.y), pk(c4.z, c4.w), pk(d4.x, d4.y), pk(d4.z, d4.w));
    }

  hbuf[0][tid] = 0;
  float c = 0.f, hl = 0.f;
  const unsigned short* xwp = xW + (size_t)n * 512 * 1024;
  __syncthreads();

  for (int t = 0; t < 512; ++t) {
    const int p = t & 1, np = p ^ 1;
    // xW for this thread's 4 gate rows (issued early, used after dots)
    unsigned short xv0 = xwp[t * 1024 + 0 * 256 + u];
    unsigned short xv1 = xwp[t * 1024 + 1 * 256 + u];
    unsigned short xv2 = xwp[t * 1024 + 2 * 256 + u];
    unsigned short xv3 = xwp[t * 1024 + 3 * 256 + u];

    // this thread's h quarter (broadcast across the 16 same-r lanes)
    unsigned hd[32];
    {
      const uint4* hb = (const uint4*)(&hbuf[p][64 * r]);
#pragma unroll
      for (int m = 0; m < 8; ++m) {
        uint4 q = hb[m];
        hd[4 * m] = q.x; hd[4 * m + 1] = q.y; hd[4 * m + 2] = q.z; hd[4 * m + 3] = q.w;
      }
    }

    float acc[16];
#pragma unroll
    for (int s = 0; s < 16; ++s) {
      float a = 0.f;
#pragma unroll
      for (int d = 0; d < 24; ++d) a = fdot2(wv[s * 24 + d], hd[d], a);
      uint4 t0 = lwL[s][0][tid];
      a = fdot2(t0.x, hd[24], a); a = fdot2(t0.y, hd[25], a);
      a = fdot2(t0.z, hd[26], a); a = fdot2(t0.w, hd[27], a);
      uint4 t1 = lwL[s][1][tid];
      a = fdot2(t1.x, hd[28], a); a = fdot2(t1.y, hd[29], a);
      a = fdot2(t1.z, hd[30], a); a = fdot2(t1.w, hd[31], a);
      acc[s] = a;
    }

    // quad rotate-reduce: lane with r==X gets full dot for row u0+X
    float A0 = acc[0] + dppf<0x93>(acc[1]) + dppf<0x4E>(acc[2]) + dppf<0x39>(acc[3]);
    float A1 = acc[4] + dppf<0x93>(acc[5]) + dppf<0x4E>(acc[6]) + dppf<0x39>(acc[7]);
    float A2 = acc[8] + dppf<0x93>(acc[9]) + dppf<0x4E>(acc[10]) + dppf<0x39>(acc[11]);
    float A3 = acc[12] + dppf<0x93>(acc[13]) + dppf<0x4E>(acc[14]) + dppf<0x39>(acc[15]);

    A0 += bias[0] + h2f(xv0);
    A1 += bias[1] + h2f(xv1);
    A2 += bias[2] + h2f(xv2);
    A3 += bias[3] + h2f(xv3);

    float iv = sigmf(A0), fv = sigmf(A1), gv = tanh_(A2), ov = sigmf(A3);
    c = fv * c + iv * gv;
    hl = ov * tanh_(c);
    unsigned short hh = f2h(hl);
    hbuf[np][u] = hh;
    if (WRITE_HS)
      hs[((size_t)n * 512 + t) * 256 + u] = hh;
    __syncthreads();
  }

  if (FINAL) {
    red[tid] = hl;
    __syncthreads();
    if (tid < 64) {
      float s = red[tid] + red[tid + 64] + red[tid + 128] + red[tid + 192];
      for (int off = 32; off > 0; off >>= 1) s += __shfl_down(s, off, 64);
      if (tid == 0) redv[0] = s * (1.f / 256.f);
    }
    __syncthreads();
    float mu = redv[0];
    red[tid] = (hl - mu) * (hl - mu);
    __syncthreads();
    if (tid < 64) {
      float s = red[tid] + red[tid + 64] + red[tid + 128] + red[tid + 192];
      for (int off = 32; off > 0; off >>= 1) s += __shfl_down(s, off, 64);
      if (tid == 0) redv[1] = s * (1.f / 256.f);
    }
    __syncthreads();
    float var = redv[1];
    out[(size_t)n * 256 + u] =
        (hl - mu) * rsqrtf(var + 1e-5f) * gamma[u] + beta[u];
  }
}

extern "C" void kernel_launch(void* const* d_in, const int* in_sizes, int n_in,
                              void* d_out, int out_size, void* d_ws, size_t ws_size,
                              hipStream_t stream) {
  const float* x     = (const float*)d_in[0];
  const float* Wih0  = (const float*)d_in[1];
  const float* Whh0  = (const float*)d_in[2];
  const float* bih0  = (const float*)d_in[3];
  const float* bhh0  = (const float*)d_in[4];
  const float* Wih1  = (const float*)d_in[5];
  const float* Whh1  = (const float*)d_in[6];
  const float* bih1  = (const float*)d_in[7];
  const float* bhh1  = (const float*)d_in[8];
  const float* gamma = (const float*)d_in[9];
  const float* beta  = (const float*)d_in[10];
  float* out = (float*)d_out;

  unsigned short* xw  = (unsigned short*)d_ws;                           // 128 MiB
  unsigned short* hs0 = (unsigned short*)((char*)d_ws + (size_t)134217728); // 32 MiB

  gemm_xw<32, 32, false><<<dim3(32, 128), 256, 0, stream>>>(x, Wih0, xw);
  lstm_rec<true, false><<<128, 256, 0, stream>>>(xw, Whh0, bih0, bhh0, hs0,
                                                 nullptr, nullptr, nullptr);
  gemm_xw<256, 128, true><<<dim3(32, 128), 256, 0, stream>>>(hs0, Wih1, xw);
  lstm_rec<false, true><<<128, 256, 0, stream>>>(xw, Whh1, bih1, bhh1, nullptr,
                                                 gamma, beta, out);
}